// Round 2
// baseline (4265.662 us; speedup 1.0000x reference)
//
#include <hip/hip_runtime.h>
#include <hip/hip_cooperative_groups.h>

namespace cg = cooperative_groups;

// TV-L1 optical flow, B=4, 512x512, 20 iters — persistent cooperative kernel.
// 256 blocks (1/CU), each owns a 64x64 tile; u1,u2,p11..p22 live in LDS
// (96 KB); gx,gy,rho_c,norm live in registers (4 px/thread x 4 vals).
// Tile-boundary halos exchanged via small global buffers + grid.sync().
// The 20th p-update is skipped (output depends only on final u).

#define HH 512
#define WW 512
#define BB 4
#define NUM_ITER 20
#define T 64          // tile edge
#define TPB 1024      // 16 waves/block, 1 block/CU (LDS-bound)
#define NBLK 256      // 4 images x 8x8 tiles

constexpr int HW = HH * WW;
constexpr float EPS = 1e-8f;

__global__ __launch_bounds__(TPB) void k_main(
    const float* __restrict__ x,
    const float* __restrict__ lam_p, const float* __restrict__ tau_p,
    const float* __restrict__ theta_p,
    const float* __restrict__ wx, const float* __restrict__ wy,
    float* __restrict__ out,
    float* __restrict__ uh,   // [NBLK][4][64]: 0=u1 Lcol,1=u1 Trow,2=u2 Lcol,3=u2 Trow
    float* __restrict__ ph,   // [NBLK][8][64]: p11L,p11R,p21L,p21R,p12T,p12B,p22T,p22B
    float* __restrict__ u1g, float* __restrict__ u2g)  // [BB*HW] final u
{
    cg::grid_group grid = cg::this_grid();

    __shared__ float su1[T*T], su2[T*T];
    __shared__ float sp11[T*T], sp12[T*T], sp21[T*T], sp22[T*T];   // 96 KB
    __shared__ float hp11l[T], hp11r[T], hp21l[T], hp21r[T];
    __shared__ float hp12t[T], hp12b[T], hp22t[T], hp22b[T];        // 2 KB
    __shared__ float hu1r[T], hu1b[T], hu2r[T], hu2b[T];            // 1 KB

    const int tid = threadIdx.x;
    const int tx  = tid & 63;          // j within tile
    const int ty  = tid >> 6;          // 0..15 (4 rows each)
    const int blk = blockIdx.x;
    const int bimg = blk >> 6;
    const int t    = blk & 63;
    const int ti = t >> 3, tj = t & 7;
    const int gi0 = ti * T, gj0 = tj * T;

    const float lam = lam_p[0], tau = tau_p[0], theta = theta_p[0];
    const float r = tau / theta;
    const float wx0 = wx[0], wx1 = wx[1], wx2 = wx[2];
    const float wy0 = wy[0], wy1 = wy[1], wy2 = wy[2];

    const float* x0 = x + (size_t)bimg * 2 * HW;
    const float* x1 = x0 + HW;

    float rgx[4], rgy[4], rrc[4], rnm[4];

    // ---------------- init: gx,gy,rho_c,norm in regs; zero LDS state ------
    for (int k = 0; k < 4; ++k) {
        int i = ty * 4 + k, j = tx;
        int gi = gi0 + i, gj = gj0 + j;
        int gij = gi * WW + gj;
        bool it_ = gi > 0, ib_ = gi < HH - 1, jl_ = gj > 0, jr_ = gj < WW - 1;
        float a00 = (it_ && jl_) ? x1[gij - WW - 1] : 0.f;
        float a01 =  it_         ? x1[gij - WW    ] : 0.f;
        float a02 = (it_ && jr_) ? x1[gij - WW + 1] : 0.f;
        float a10 =  jl_         ? x1[gij - 1     ] : 0.f;
        float a12 =  jr_         ? x1[gij + 1     ] : 0.f;
        float a20 = (ib_ && jl_) ? x1[gij + WW - 1] : 0.f;
        float a21 =  ib_         ? x1[gij + WW    ] : 0.f;
        float a22 = (ib_ && jr_) ? x1[gij + WW + 1] : 0.f;
        const float c6 = 1.f / 6.f;
        float gxv = c6 * (-a00 + a02 - 2.f * a10 + 2.f * a12 - a20 + a22);
        float gyv = c6 * (-a00 - 2.f * a01 - a02 + a20 + 2.f * a21 + a22);
        rgx[k] = gxv; rgy[k] = gyv;
        rrc[k] = x1[gij] - x0[gij];
        rnm[k] = gxv * gxv + gyv * gyv + EPS;
        int idx = i * T + j;
        su1[idx] = 0.f;  su2[idx] = 0.f;
        sp11[idx] = 0.f; sp12[idx] = 0.f; sp21[idx] = 0.f; sp22[idx] = 0.f;
    }
    // zero this block's published halo slots (ws is poisoned 0xAA)
    if (tid < 4 * T)                      uh[blk * 4 * T + tid] = 0.f;
    else if (tid < 4 * T + 8 * T)         ph[blk * 8 * T + (tid - 4 * T)] = 0.f;
    __threadfence();
    grid.sync();

    for (int it = 0; it < NUM_ITER; ++it) {
        // ---- preload p halos into LDS (one wave per array; g uniform/wave)
        {
            int g = tid >> 6, l = tid & 63;
            if (g < 8) {
                float v = 0.f;
                switch (g) {
                    case 0: if (tj > 0) v = ph[(blk - 1) * 512 + 1 * 64 + l]; hp11l[l] = v; break;
                    case 1: if (tj < 7) v = ph[(blk + 1) * 512 + 0 * 64 + l]; hp11r[l] = v; break;
                    case 2: if (tj > 0) v = ph[(blk - 1) * 512 + 3 * 64 + l]; hp21l[l] = v; break;
                    case 3: if (tj < 7) v = ph[(blk + 1) * 512 + 2 * 64 + l]; hp21r[l] = v; break;
                    case 4: if (ti > 0) v = ph[(blk - 8) * 512 + 5 * 64 + l]; hp12t[l] = v; break;
                    case 5: if (ti < 7) v = ph[(blk + 8) * 512 + 4 * 64 + l]; hp12b[l] = v; break;
                    case 6: if (ti > 0) v = ph[(blk - 8) * 512 + 7 * 64 + l]; hp22t[l] = v; break;
                    case 7: if (ti < 7) v = ph[(blk + 8) * 512 + 6 * 64 + l]; hp22b[l] = v; break;
                }
            }
        }
        __syncthreads();

        // ---- phase U: u_new = v + theta*div(p_old); in-place per-pixel ---
        const bool last = (it == NUM_ITER - 1);
        for (int k = 0; k < 4; ++k) {
            int i = ty * 4 + k, j = tx, idx = i * T + j;
            float u1v = su1[idx], u2v = su2[idx];
            float rho = rrc[k] + rgx[k] * u1v + rgy[k] * u2v;
            float th  = theta * lam * rnm[k];
            float v1, v2;
            if (fabsf(rho) < th) {
                float d = rho / rnm[k];
                v1 = u1v - d * rgx[k];
                v2 = u2v - d * rgy[k];
            } else {
                float sgn = (rho > 0.f) ? 1.f : ((rho < 0.f) ? -1.f : 0.f);
                float s = theta * lam * sgn;
                v1 = u1v - s * rgx[k];
                v2 = u2v - s * rgy[k];
            }
            float p11l = j > 0  ? sp11[idx - 1] : hp11l[i];
            float p11r = j < 63 ? sp11[idx + 1] : hp11r[i];
            float p12t = i > 0  ? sp12[idx - T] : hp12t[j];
            float p12b = i < 63 ? sp12[idx + T] : hp12b[j];
            float div1 = wx0 * p11l + wx1 * sp11[idx] + wx2 * p11r
                       + wy0 * p12t + wy1 * sp12[idx] + wy2 * p12b;
            float p21l = j > 0  ? sp21[idx - 1] : hp21l[i];
            float p21r = j < 63 ? sp21[idx + 1] : hp21r[i];
            float p22t = i > 0  ? sp22[idx - T] : hp22t[j];
            float p22b = i < 63 ? sp22[idx + T] : hp22b[j];
            float div2 = wx0 * p21l + wx1 * sp21[idx] + wx2 * p21r
                       + wy0 * p22t + wy1 * sp22[idx] + wy2 * p22b;
            float nu1 = v1 + theta * div1;
            float nu2 = v2 + theta * div2;
            su1[idx] = nu1; su2[idx] = nu2;
            if (j == 0) { uh[blk * 256 + 0 * 64 + i] = nu1; uh[blk * 256 + 2 * 64 + i] = nu2; }
            if (i == 0) { uh[blk * 256 + 1 * 64 + j] = nu1; uh[blk * 256 + 3 * 64 + j] = nu2; }
            if (last) {
                int gidx = bimg * HW + (gi0 + i) * WW + gj0 + j;
                u1g[gidx] = nu1; u2g[gidx] = nu2;
            }
        }
        __threadfence();
        grid.sync();
        if (last) break;     // 20th p-update is dead code

        // ---- preload u halos (right col / bottom row from neighbors) -----
        {
            int g = tid >> 6, l = tid & 63;
            if (g < 4) {
                float v = 0.f;
                switch (g) {
                    case 0: if (tj < 7) v = uh[(blk + 1) * 256 + 0 * 64 + l]; hu1r[l] = v; break;
                    case 1: if (ti < 7) v = uh[(blk + 8) * 256 + 1 * 64 + l]; hu1b[l] = v; break;
                    case 2: if (tj < 7) v = uh[(blk + 1) * 256 + 2 * 64 + l]; hu2r[l] = v; break;
                    case 3: if (ti < 7) v = uh[(blk + 8) * 256 + 3 * 64 + l]; hu2b[l] = v; break;
                }
            }
        }
        __syncthreads();

        // ---- phase P: p_new = (p + r*gu)/(1 + r*|gu|_1); in-place --------
        for (int k = 0; k < 4; ++k) {
            int i = ty * 4 + k, j = tx, idx = i * T + j;
            float u1c = su1[idx];
            float u1r = j < 63 ? su1[idx + 1] : hu1r[i];
            float u1b = i < 63 ? su1[idx + T] : hu1b[j];
            float u2c = su2[idx];
            float u2r = j < 63 ? su2[idx + 1] : hu2r[i];
            float u2b = i < 63 ? su2[idx + T] : hu2b[j];
            float gu1x = u1r - u1c, gu1y = u1b - u1c;
            float gu2x = u2r - u2c, gu2y = u2b - u2c;
            float d1 = 1.f + r * (fabsf(gu1x) + fabsf(gu1y));
            float np11 = (sp11[idx] + r * gu1x) / d1;
            float np12 = (sp12[idx] + r * gu1y) / d1;
            float d2 = 1.f + r * (fabsf(gu2x) + fabsf(gu2y));
            float np21 = (sp21[idx] + r * gu2x) / d2;
            float np22 = (sp22[idx] + r * gu2y) / d2;
            sp11[idx] = np11; sp12[idx] = np12; sp21[idx] = np21; sp22[idx] = np22;
            if (j == 0)  { ph[blk * 512 + 0 * 64 + i] = np11; ph[blk * 512 + 2 * 64 + i] = np21; }
            if (j == 63) { ph[blk * 512 + 1 * 64 + i] = np11; ph[blk * 512 + 3 * 64 + i] = np21; }
            if (i == 0)  { ph[blk * 512 + 4 * 64 + j] = np12; ph[blk * 512 + 6 * 64 + j] = np22; }
            if (i == 63) { ph[blk * 512 + 5 * 64 + j] = np12; ph[blk * 512 + 7 * 64 + j] = np22; }
        }
        __threadfence();
        grid.sync();
    }

    // ---- avgpool(3,1,1, count_include_pad) on final u, via global u ------
    for (int k = 0; k < 4; ++k) {
        int i = ty * 4 + k, j = tx;
        int gi = gi0 + i, gj = gj0 + j;
        int i0_ = gi > 0 ? gi - 1 : gi, i1_ = gi < HH - 1 ? gi + 1 : gi;
        int j0_ = gj > 0 ? gj - 1 : gj, j1_ = gj < WW - 1 ? gj + 1 : gj;
        float s1 = 0.f, s2 = 0.f;
        const float* u1b = u1g + (size_t)bimg * HW;
        const float* u2b = u2g + (size_t)bimg * HW;
        for (int ii = i0_; ii <= i1_; ++ii)
            for (int jj = j0_; jj <= j1_; ++jj) {
                s1 += u1b[ii * WW + jj];
                s2 += u2b[ii * WW + jj];
            }
        const float inv9 = 1.f / 9.f;
        out[((size_t)bimg * 2 + 0) * HW + gi * WW + gj] = s1 * inv9;
        out[((size_t)bimg * 2 + 1) * HW + gi * WW + gj] = s2 * inv9;
    }
}

// --------------------------------------------------------------- launch ---
extern "C" void kernel_launch(void* const* d_in, const int* in_sizes, int n_in,
                              void* d_out, int out_size, void* d_ws, size_t ws_size,
                              hipStream_t stream) {
    const float* x     = (const float*)d_in[0];
    const float* lam   = (const float*)d_in[1];
    const float* tau   = (const float*)d_in[2];
    const float* theta = (const float*)d_in[3];
    const float* wx    = (const float*)d_in[4];
    const float* wy    = (const float*)d_in[5];
    float* out = (float*)d_out;

    float* ws  = (float*)d_ws;
    float* uh  = ws;                         // 256*4*64   = 65,536 floats
    float* ph  = uh + NBLK * 4 * T;          // 256*8*64   = 131,072
    float* u1g = ph + NBLK * 8 * T;          // 1,048,576
    float* u2g = u1g + (size_t)BB * HW;      // 1,048,576

    void* args[] = {
        (void*)&x, (void*)&lam, (void*)&tau, (void*)&theta,
        (void*)&wx, (void*)&wy, (void*)&out,
        (void*)&uh, (void*)&ph, (void*)&u1g, (void*)&u2g
    };
    hipLaunchCooperativeKernel((const void*)k_main, dim3(NBLK), dim3(TPB),
                               args, 0, stream);
}

// Round 3
// 245.038 us; speedup vs baseline: 17.4082x; 17.4082x over previous
//
#include <hip/hip_runtime.h>

// TV-L1 optical flow, B=4, 512x512, 20 iters — temporal blocking (ghost zones).
// 5 launches: k_init + 4 x k_fused(5 iterations each, in LDS).
// Each block owns a 64x64 output tile but loads/evolves an 80x80 region
// (halo: 6 left/top, 10 right/bottom — p's dependency cone grows +1 left,
// +2 right per iteration). u1,u2,p11..p22 live in LDS (153.6 KB);
// gx,gy,rho_c,norm live in registers (7 px/thread).
// Zero-padding reproduced by forcing u=p=0 on out-of-image pixels.
// Last kernel skips the dead 20th p-update and fuses the 3x3 avgpool.

#define HH 512
#define WW 512
#define BB 4
constexpr int HW   = HH * WW;
constexpr int NTOT = BB * HW;
constexpr float EPS = 1e-8f;

#define T 64          // output tile edge
#define HALO_L 6      // left/top halo
#define REG 80        // region edge = 64 + 6 + 10
#define NPX (REG * REG)   // 6400
#define TPB 1024
#define SLOTS 7       // ceil(6400/1024)
#define NBLK 256      // 4 images x 8x8 tiles

// ---------------------------------------------------------------- init ----
__global__ void k_init(const float* __restrict__ x,
                       float* __restrict__ gx, float* __restrict__ gy,
                       float* __restrict__ rc, float* __restrict__ nm) {
    int idx = blockIdx.x * blockDim.x + threadIdx.x;
    if (idx >= NTOT) return;
    int b  = idx / HW;
    int ij = idx - b * HW;
    int i  = ij / WW;
    int j  = ij - i * WW;
    const float* x0 = x + (size_t)b * 2 * HW;
    const float* x1 = x0 + HW;
    bool it_ = i > 0, ib_ = i < HH - 1, jl_ = j > 0, jr_ = j < WW - 1;
    float a00 = (it_ && jl_) ? x1[ij - WW - 1] : 0.f;
    float a01 =  it_         ? x1[ij - WW    ] : 0.f;
    float a02 = (it_ && jr_) ? x1[ij - WW + 1] : 0.f;
    float a10 =  jl_         ? x1[ij - 1     ] : 0.f;
    float a12 =  jr_         ? x1[ij + 1     ] : 0.f;
    float a20 = (ib_ && jl_) ? x1[ij + WW - 1] : 0.f;
    float a21 =  ib_         ? x1[ij + WW    ] : 0.f;
    float a22 = (ib_ && jr_) ? x1[ij + WW + 1] : 0.f;
    const float c6 = 1.f / 6.f;
    float gxv = c6 * (-a00 + a02 - 2.f * a10 + 2.f * a12 - a20 + a22);
    float gyv = c6 * (-a00 - 2.f * a01 - a02 + a20 + 2.f * a21 + a22);
    gx[idx] = gxv;
    gy[idx] = gyv;
    rc[idx] = x1[ij] - x0[ij];
    nm[idx] = gxv * gxv + gyv * gyv + EPS;
}

// ------------------------------------------------- fused 5-iteration ------
// phase: 0 = first (u,p start at zero, write back), 1 = middle (load, write
// back), 2 = last (load, 5 u-phases + 4 p-phases, fused avgpool -> out).
__global__ __launch_bounds__(TPB) void k_fused(
    const float* __restrict__ gxg, const float* __restrict__ gyg,
    const float* __restrict__ rcg, const float* __restrict__ nmg,
    float* __restrict__ u1g, float* __restrict__ u2g,
    float* __restrict__ p11g, float* __restrict__ p12g,
    float* __restrict__ p21g, float* __restrict__ p22g,
    const float* __restrict__ lam_p, const float* __restrict__ tau_p,
    const float* __restrict__ theta_p,
    const float* __restrict__ wxp, const float* __restrict__ wyp,
    float* __restrict__ out, int phase)
{
    __shared__ float su1[NPX], su2[NPX];
    __shared__ float sp11[NPX], sp12[NPX], sp21[NPX], sp22[NPX];  // 153.6 KB

    const int tid  = threadIdx.x;
    const int blk  = blockIdx.x;
    const int bimg = blk >> 6;
    const int t    = blk & 63;
    const int gi0  = (t >> 3) * T;
    const int gj0  = (t & 7) * T;

    const float lam = lam_p[0], theta = theta_p[0];
    const float r   = tau_p[0] / theta;
    const float tl  = theta * lam;
    const float wx0 = wxp[0], wx1 = wxp[1], wx2 = wxp[2];
    const float wy0 = wyp[0], wy1 = wyp[1], wy2 = wyp[2];

    const size_t base = (size_t)bimg * HW;

    float rgx[SLOTS], rgy[SLOTS], rrc[SLOTS], rnm[SLOTS];

    // ---- load static fields into regs; load or zero u,p in LDS ----------
    #pragma unroll
    for (int s = 0; s < SLOTS; ++s) {
        int idx = tid + s * TPB;
        if (idx >= NPX) break;
        int li = idx / REG, lj = idx - li * REG;
        int gi = gi0 + li - HALO_L, gj = gj0 + lj - HALO_L;
        bool in = (gi >= 0) & (gi < HH) & (gj >= 0) & (gj < WW);
        size_t g = base + (size_t)gi * WW + gj;   // only deref when in
        rgx[s] = in ? gxg[g] : 0.f;
        rgy[s] = in ? gyg[g] : 0.f;
        rrc[s] = in ? rcg[g] : 0.f;
        rnm[s] = in ? nmg[g] : EPS;
        if (phase == 0) {
            su1[idx] = 0.f;  su2[idx] = 0.f;
            sp11[idx] = 0.f; sp12[idx] = 0.f; sp21[idx] = 0.f; sp22[idx] = 0.f;
        } else {
            su1[idx]  = in ? u1g[g]  : 0.f;
            su2[idx]  = in ? u2g[g]  : 0.f;
            sp11[idx] = in ? p11g[g] : 0.f;
            sp12[idx] = in ? p12g[g] : 0.f;
            sp21[idx] = in ? p21g[g] : 0.f;
            sp22[idx] = in ? p22g[g] : 0.f;
        }
    }
    __syncthreads();

    // ---- 5 fused iterations --------------------------------------------
    for (int k = 1; k <= 5; ++k) {
        // u-phase over li,lj in [k, 80-2k]  (valid cone of u^k)
        const int lo = k, hi_u = REG - 2 * k;
        #pragma unroll
        for (int s = 0; s < SLOTS; ++s) {
            int idx = tid + s * TPB;
            if (idx >= NPX) break;
            int li = idx / REG, lj = idx - li * REG;
            if (li < lo || li > hi_u || lj < lo || lj > hi_u) continue;
            float u1v = su1[idx], u2v = su2[idx];
            float rho = rrc[s] + rgx[s] * u1v + rgy[s] * u2v;
            float th  = tl * rnm[s];
            float v1, v2;
            if (fabsf(rho) < th) {
                float d = rho / rnm[s];
                v1 = u1v - d * rgx[s];
                v2 = u2v - d * rgy[s];
            } else {
                float sgn = (rho > 0.f) ? 1.f : ((rho < 0.f) ? -1.f : 0.f);
                float ss = tl * sgn;
                v1 = u1v - ss * rgx[s];
                v2 = u2v - ss * rgy[s];
            }
            float div1 = wx0 * sp11[idx - 1]   + wx1 * sp11[idx] + wx2 * sp11[idx + 1]
                       + wy0 * sp12[idx - REG] + wy1 * sp12[idx] + wy2 * sp12[idx + REG];
            float div2 = wx0 * sp21[idx - 1]   + wx1 * sp21[idx] + wx2 * sp21[idx + 1]
                       + wy0 * sp22[idx - REG] + wy1 * sp22[idx] + wy2 * sp22[idx + REG];
            float nu1 = v1 + theta * div1;
            float nu2 = v2 + theta * div2;
            int gi = gi0 + li - HALO_L, gj = gj0 + lj - HALO_L;
            bool in = (gi >= 0) & (gi < HH) & (gj >= 0) & (gj < WW);
            if (!in) { nu1 = 0.f; nu2 = 0.f; }   // zero-padding semantics
            su1[idx] = nu1; su2[idx] = nu2;
        }
        __syncthreads();
        if (phase == 2 && k == 5) break;   // 20th p-update is dead code

        // p-phase over li,lj in [k, 79-2k]  (valid cone of p^k)
        const int hi_p = REG - 1 - 2 * k;
        #pragma unroll
        for (int s = 0; s < SLOTS; ++s) {
            int idx = tid + s * TPB;
            if (idx >= NPX) break;
            int li = idx / REG, lj = idx - li * REG;
            if (li < lo || li > hi_p || lj < lo || lj > hi_p) continue;
            float u1c = su1[idx];
            float gu1x = su1[idx + 1]   - u1c;
            float gu1y = su1[idx + REG] - u1c;
            float u2c = su2[idx];
            float gu2x = su2[idx + 1]   - u2c;
            float gu2y = su2[idx + REG] - u2c;
            float d1 = 1.f + r * (fabsf(gu1x) + fabsf(gu1y));
            float np11 = (sp11[idx] + r * gu1x) / d1;
            float np12 = (sp12[idx] + r * gu1y) / d1;
            float d2 = 1.f + r * (fabsf(gu2x) + fabsf(gu2y));
            float np21 = (sp21[idx] + r * gu2x) / d2;
            float np22 = (sp22[idx] + r * gu2y) / d2;
            int gi = gi0 + li - HALO_L, gj = gj0 + lj - HALO_L;
            bool in = (gi >= 0) & (gi < HH) & (gj >= 0) & (gj < WW);
            if (!in) { np11 = 0.f; np12 = 0.f; np21 = 0.f; np22 = 0.f; }
            sp11[idx] = np11; sp12[idx] = np12;
            sp21[idx] = np21; sp22[idx] = np22;
        }
        __syncthreads();
    }

    // ---- epilogue -------------------------------------------------------
    if (phase != 2) {
        // write back interior [0,63]^2 (li,lj in [6,69])
        #pragma unroll
        for (int s = 0; s < SLOTS; ++s) {
            int idx = tid + s * TPB;
            if (idx >= NPX) break;
            int li = idx / REG, lj = idx - li * REG;
            if (li < HALO_L || li >= HALO_L + T || lj < HALO_L || lj >= HALO_L + T) continue;
            int gi = gi0 + li - HALO_L, gj = gj0 + lj - HALO_L;
            size_t g = base + (size_t)gi * WW + gj;
            u1g[g]  = su1[idx];  u2g[g]  = su2[idx];
            p11g[g] = sp11[idx]; p12g[g] = sp12[idx];
            p21g[g] = sp21[idx]; p22g[g] = sp22[idx];
        }
    } else {
        // fused avgpool(3,1,1, /9 always); u^5 valid on [-1,64] — exact fit
        const float inv9 = 1.f / 9.f;
        #pragma unroll
        for (int s = 0; s < SLOTS; ++s) {
            int idx = tid + s * TPB;
            if (idx >= NPX) break;
            int li = idx / REG, lj = idx - li * REG;
            if (li < HALO_L || li >= HALO_L + T || lj < HALO_L || lj >= HALO_L + T) continue;
            float s1 = su1[idx - REG - 1] + su1[idx - REG] + su1[idx - REG + 1]
                     + su1[idx - 1]       + su1[idx]       + su1[idx + 1]
                     + su1[idx + REG - 1] + su1[idx + REG] + su1[idx + REG + 1];
            float s2 = su2[idx - REG - 1] + su2[idx - REG] + su2[idx - REG + 1]
                     + su2[idx - 1]       + su2[idx]       + su2[idx + 1]
                     + su2[idx + REG - 1] + su2[idx + REG] + su2[idx + REG + 1];
            int gi = gi0 + li - HALO_L, gj = gj0 + lj - HALO_L;
            out[((size_t)bimg * 2 + 0) * HW + (size_t)gi * WW + gj] = s1 * inv9;
            out[((size_t)bimg * 2 + 1) * HW + (size_t)gi * WW + gj] = s2 * inv9;
        }
    }
}

// --------------------------------------------------------------- launch ---
extern "C" void kernel_launch(void* const* d_in, const int* in_sizes, int n_in,
                              void* d_out, int out_size, void* d_ws, size_t ws_size,
                              hipStream_t stream) {
    const float* x     = (const float*)d_in[0];
    const float* lam   = (const float*)d_in[1];
    const float* tau   = (const float*)d_in[2];
    const float* theta = (const float*)d_in[3];
    const float* wx    = (const float*)d_in[4];
    const float* wy    = (const float*)d_in[5];
    float* out = (float*)d_out;

    float* ws  = (float*)d_ws;
    float* gx  = ws + (size_t)0 * NTOT;
    float* gy  = ws + (size_t)1 * NTOT;
    float* rc  = ws + (size_t)2 * NTOT;
    float* nm  = ws + (size_t)3 * NTOT;
    float* u1  = ws + (size_t)4 * NTOT;
    float* u2  = ws + (size_t)5 * NTOT;
    float* p11 = ws + (size_t)6 * NTOT;
    float* p12 = ws + (size_t)7 * NTOT;
    float* p21 = ws + (size_t)8 * NTOT;
    float* p22 = ws + (size_t)9 * NTOT;

    k_init<<<dim3((NTOT + 255) / 256), dim3(256), 0, stream>>>(x, gx, gy, rc, nm);

    for (int c = 0; c < 4; ++c) {
        int phase = (c == 0) ? 0 : (c == 3) ? 2 : 1;
        k_fused<<<dim3(NBLK), dim3(TPB), 0, stream>>>(
            gx, gy, rc, nm, u1, u2, p11, p12, p21, p22,
            lam, tau, theta, wx, wy, out, phase);
    }
}

// Round 4
// 195.157 us; speedup vs baseline: 21.8576x; 1.2556x over previous
//
#include <hip/hip_runtime.h>

// TV-L1 optical flow, B=4, 512x512, 20 iters — temporal blocking (ghost zones)
// R4: float2-paired LDS state + per-thread register mirrors.
//   LDS: su=(u1,u2), spa=(p11,p21), spb=(p12,p22), 3 x 6400 x 8B = 153.6 KB.
//   Regs: each thread owns 7 slots; own-pixel u/p mirrored in VGPRs so the
//   u-phase does 4 ds_read_b64 + 1 ds_write_b64, p-phase 2 + 2 (was ~30 b32).
// 5 launches: k_init + 4 x k_fused(5 iters). Halo L=6/R=10 (80x80 region).
// Zero-padding reproduced by forcing u=p=0 on out-of-image pixels.
// Last kernel skips the dead 20th p-update and fuses the 3x3 avgpool.

#define HH 512
#define WW 512
#define BB 4
constexpr int HW   = HH * WW;
constexpr int NTOT = BB * HW;
constexpr float EPS = 1e-8f;

#define T 64          // output tile edge
#define HALO_L 6      // left/top halo
#define REG 80        // region edge = 64 + 6 + 10
#define NPX (REG * REG)   // 6400
#define TPB 1024
#define SLOTS 7       // ceil(6400/1024)
#define NBLK 256      // 4 images x 8x8 tiles

// ---------------------------------------------------------------- init ----
// Writes paired statics: g2=(gx,gy), rn=(rho_c, norm).
__global__ void k_init(const float* __restrict__ x,
                       float2* __restrict__ g2, float2* __restrict__ rn) {
    int idx = blockIdx.x * blockDim.x + threadIdx.x;
    if (idx >= NTOT) return;
    int b  = idx / HW;
    int ij = idx - b * HW;
    int i  = ij / WW;
    int j  = ij - i * WW;
    const float* x0 = x + (size_t)b * 2 * HW;
    const float* x1 = x0 + HW;
    bool it_ = i > 0, ib_ = i < HH - 1, jl_ = j > 0, jr_ = j < WW - 1;
    float a00 = (it_ && jl_) ? x1[ij - WW - 1] : 0.f;
    float a01 =  it_         ? x1[ij - WW    ] : 0.f;
    float a02 = (it_ && jr_) ? x1[ij - WW + 1] : 0.f;
    float a10 =  jl_         ? x1[ij - 1     ] : 0.f;
    float a12 =  jr_         ? x1[ij + 1     ] : 0.f;
    float a20 = (ib_ && jl_) ? x1[ij + WW - 1] : 0.f;
    float a21 =  ib_         ? x1[ij + WW    ] : 0.f;
    float a22 = (ib_ && jr_) ? x1[ij + WW + 1] : 0.f;
    const float c6 = 1.f / 6.f;
    float gxv = c6 * (-a00 + a02 - 2.f * a10 + 2.f * a12 - a20 + a22);
    float gyv = c6 * (-a00 - 2.f * a01 - a02 + a20 + 2.f * a21 + a22);
    g2[idx] = make_float2(gxv, gyv);
    rn[idx] = make_float2(x1[ij] - x0[ij], gxv * gxv + gyv * gyv + EPS);
}

// ------------------------------------------------- fused 5-iteration ------
// phase: 0 = first (u,p zero-init, write back), 1 = middle (load, write
// back), 2 = last (load, 5 u-phases + 4 p-phases, fused avgpool -> out).
__global__ __launch_bounds__(TPB, 1) void k_fused(
    const float2* __restrict__ g2g, const float2* __restrict__ rng,
    float2* __restrict__ ug, float2* __restrict__ pag, float2* __restrict__ pbg,
    const float* __restrict__ lam_p, const float* __restrict__ tau_p,
    const float* __restrict__ theta_p,
    const float* __restrict__ wxp, const float* __restrict__ wyp,
    float* __restrict__ out, int phase)
{
    __shared__ float2 su[NPX];    // (u1,u2)
    __shared__ float2 spa[NPX];   // (p11,p21)
    __shared__ float2 spb[NPX];   // (p12,p22)   -> 153.6 KB total

    const int tid  = threadIdx.x;
    const int blk  = blockIdx.x;
    const int bimg = blk >> 6;
    const int t    = blk & 63;
    const int gi0  = (t >> 3) * T;
    const int gj0  = (t & 7) * T;

    const float lam = lam_p[0], theta = theta_p[0];
    const float r   = tau_p[0] / theta;
    const float tl  = theta * lam;
    const float wx0 = wxp[0], wx1 = wxp[1], wx2 = wxp[2];
    const float wy0 = wyp[0], wy1 = wyp[1], wy2 = wyp[2];

    const size_t base = (size_t)bimg * HW;

    float  rgx[SLOTS], rgy[SLOTS], rrc[SLOTS], rth[SLOTS], rnv[SLOTS];
    float2 ruv[SLOTS], rpa[SLOTS], rpb[SLOTS];   // own-pixel mirrors

    // ---- load statics into regs; load-or-zero state into LDS + mirrors --
    #pragma unroll
    for (int s = 0; s < SLOTS; ++s) {
        int idx = tid + s * TPB;
        if (idx >= NPX) break;
        int li = idx / REG, lj = idx - li * REG;
        int gi = gi0 + li - HALO_L, gj = gj0 + lj - HALO_L;
        bool in = ((unsigned)gi < HH) & ((unsigned)gj < WW);
        size_t g = base + (size_t)gi * WW + gj;   // deref only when in
        float2 gv = in ? g2g[g] : make_float2(0.f, 0.f);
        float2 rv = in ? rng[g] : make_float2(0.f, EPS);
        rgx[s] = gv.x; rgy[s] = gv.y; rrc[s] = rv.x;
        rth[s] = tl * rv.y;
        rnv[s] = __builtin_amdgcn_rcpf(rv.y);
        float2 z = make_float2(0.f, 0.f);
        float2 uv = z, pa = z, pb = z;
        if (phase != 0 && in) { uv = ug[g]; pa = pag[g]; pb = pbg[g]; }
        su[idx] = uv; spa[idx] = pa; spb[idx] = pb;
        ruv[s] = uv; rpa[s] = pa; rpb[s] = pb;
    }
    __syncthreads();

    // ---- 5 fused iterations --------------------------------------------
    for (int k = 1; k <= 5; ++k) {
        // u-phase over li,lj in [k, REG-2k]  (valid cone of u^k)
        const int lo = k, hi_u = REG - 2 * k;
        #pragma unroll
        for (int s = 0; s < SLOTS; ++s) {
            int idx = tid + s * TPB;
            if (idx >= NPX) break;
            int li = idx / REG, lj = idx - li * REG;
            if (li < lo || li > hi_u || lj < lo || lj > hi_u) continue;
            float2 uv = ruv[s];
            float rho = rrc[s] + rgx[s] * uv.x + rgy[s] * uv.y;
            float v1, v2;
            if (fabsf(rho) < rth[s]) {
                float d = rho * rnv[s];
                v1 = uv.x - d * rgx[s];
                v2 = uv.y - d * rgy[s];
            } else {
                float sgn = (rho > 0.f) ? 1.f : ((rho < 0.f) ? -1.f : 0.f);
                float ss = tl * sgn;
                v1 = uv.x - ss * rgx[s];
                v2 = uv.y - ss * rgy[s];
            }
            float2 pal = spa[idx - 1],   par = spa[idx + 1];
            float2 pbt = spb[idx - REG], pbb = spb[idx + REG];
            float2 pac = rpa[s],         pbc = rpb[s];
            float div1 = wx0 * pal.x + wx1 * pac.x + wx2 * par.x
                       + wy0 * pbt.x + wy1 * pbc.x + wy2 * pbb.x;
            float div2 = wx0 * pal.y + wx1 * pac.y + wx2 * par.y
                       + wy0 * pbt.y + wy1 * pbc.y + wy2 * pbb.y;
            float nu1 = v1 + theta * div1;
            float nu2 = v2 + theta * div2;
            int gi = gi0 + li - HALO_L, gj = gj0 + lj - HALO_L;
            bool in = ((unsigned)gi < HH) & ((unsigned)gj < WW);
            if (!in) { nu1 = 0.f; nu2 = 0.f; }   // zero-padding semantics
            float2 nuv = make_float2(nu1, nu2);
            ruv[s] = nuv; su[idx] = nuv;
        }
        __syncthreads();
        if (phase == 2 && k == 5) break;   // 20th p-update is dead code

        // p-phase over li,lj in [k, REG-1-2k]  (valid cone of p^k)
        const int hi_p = REG - 1 - 2 * k;
        #pragma unroll
        for (int s = 0; s < SLOTS; ++s) {
            int idx = tid + s * TPB;
            if (idx >= NPX) break;
            int li = idx / REG, lj = idx - li * REG;
            if (li < lo || li > hi_p || lj < lo || lj > hi_p) continue;
            float2 uc = ruv[s];
            float2 ur = su[idx + 1];
            float2 ub = su[idx + REG];
            float gu1x = ur.x - uc.x, gu1y = ub.x - uc.x;
            float gu2x = ur.y - uc.y, gu2y = ub.y - uc.y;
            float d1 = 1.f + r * (fabsf(gu1x) + fabsf(gu1y));
            float id1 = __builtin_amdgcn_rcpf(d1);
            float np11 = (rpa[s].x + r * gu1x) * id1;
            float np12 = (rpb[s].x + r * gu1y) * id1;
            float d2 = 1.f + r * (fabsf(gu2x) + fabsf(gu2y));
            float id2 = __builtin_amdgcn_rcpf(d2);
            float np21 = (rpa[s].y + r * gu2x) * id2;
            float np22 = (rpb[s].y + r * gu2y) * id2;
            int gi = gi0 + li - HALO_L, gj = gj0 + lj - HALO_L;
            bool in = ((unsigned)gi < HH) & ((unsigned)gj < WW);
            if (!in) { np11 = 0.f; np12 = 0.f; np21 = 0.f; np22 = 0.f; }
            float2 npa = make_float2(np11, np21);
            float2 npb = make_float2(np12, np22);
            rpa[s] = npa; rpb[s] = npb;
            spa[idx] = npa; spb[idx] = npb;
        }
        __syncthreads();
    }

    // ---- epilogue -------------------------------------------------------
    if (phase != 2) {
        // write back interior [0,63]^2 (li,lj in [6,69])
        #pragma unroll
        for (int s = 0; s < SLOTS; ++s) {
            int idx = tid + s * TPB;
            if (idx >= NPX) break;
            int li = idx / REG, lj = idx - li * REG;
            if (li < HALO_L || li >= HALO_L + T || lj < HALO_L || lj >= HALO_L + T) continue;
            int gi = gi0 + li - HALO_L, gj = gj0 + lj - HALO_L;
            size_t g = base + (size_t)gi * WW + gj;
            ug[g] = ruv[s]; pag[g] = rpa[s]; pbg[g] = rpb[s];
        }
    } else {
        // fused avgpool(3,1,1, /9 always); u^5 valid on [-1,64] — exact fit
        const float inv9 = 1.f / 9.f;
        #pragma unroll
        for (int s = 0; s < SLOTS; ++s) {
            int idx = tid + s * TPB;
            if (idx >= NPX) break;
            int li = idx / REG, lj = idx - li * REG;
            if (li < HALO_L || li >= HALO_L + T || lj < HALO_L || lj >= HALO_L + T) continue;
            float2 a0 = su[idx - REG - 1], a1 = su[idx - REG], a2 = su[idx - REG + 1];
            float2 b0 = su[idx - 1],       b1 = su[idx],       b2 = su[idx + 1];
            float2 c0 = su[idx + REG - 1], c1 = su[idx + REG], c2 = su[idx + REG + 1];
            float s1 = a0.x + a1.x + a2.x + b0.x + b1.x + b2.x + c0.x + c1.x + c2.x;
            float s2 = a0.y + a1.y + a2.y + b0.y + b1.y + b2.y + c0.y + c1.y + c2.y;
            int gi = gi0 + li - HALO_L, gj = gj0 + lj - HALO_L;
            out[((size_t)bimg * 2 + 0) * HW + (size_t)gi * WW + gj] = s1 * inv9;
            out[((size_t)bimg * 2 + 1) * HW + (size_t)gi * WW + gj] = s2 * inv9;
        }
    }
}

// --------------------------------------------------------------- launch ---
extern "C" void kernel_launch(void* const* d_in, const int* in_sizes, int n_in,
                              void* d_out, int out_size, void* d_ws, size_t ws_size,
                              hipStream_t stream) {
    const float* x     = (const float*)d_in[0];
    const float* lam   = (const float*)d_in[1];
    const float* tau   = (const float*)d_in[2];
    const float* theta = (const float*)d_in[3];
    const float* wx    = (const float*)d_in[4];
    const float* wy    = (const float*)d_in[5];
    float* out = (float*)d_out;

    float2* ws  = (float2*)d_ws;
    float2* g2  = ws + (size_t)0 * NTOT;
    float2* rn  = ws + (size_t)1 * NTOT;
    float2* ug  = ws + (size_t)2 * NTOT;
    float2* pa  = ws + (size_t)3 * NTOT;
    float2* pb  = ws + (size_t)4 * NTOT;

    k_init<<<dim3((NTOT + 255) / 256), dim3(256), 0, stream>>>(x, g2, rn);

    for (int c = 0; c < 4; ++c) {
        int phase = (c == 0) ? 0 : (c == 3) ? 2 : 1;
        k_fused<<<dim3(NBLK), dim3(TPB), 0, stream>>>(
            g2, rn, ug, pa, pb, lam, tau, theta, wx, wy, out, phase);
    }
}

// Round 5
// 184.684 us; speedup vs baseline: 23.0971x; 1.0567x over previous
//
#include <hip/hip_runtime.h>

// TV-L1 optical flow, B=4, 512x512, 20 iters — temporal blocking (ghost zones)
// R5: 4 launches only (k_init folded into k_fused: statics recomputed from x
// via an 82x82 LDS staging pass through spa). Hoisted per-slot indices,
// branchless rho-select, float4-packed global p-state, unroll-friendly guards.
//   LDS: su=(u1,u2), spa=(p11,p21), spb=(p12,p22), 3 x 6400 x 8B = 153.6 KB.
// Halo L=6/R=10 (80x80 region per 64x64 tile). Zero-padding reproduced by
// forcing u=p=0 on out-of-image pixels. Last kernel skips the dead 20th
// p-update and fuses the 3x3 avgpool.

#define HH 512
#define WW 512
#define BB 4
constexpr int HW   = HH * WW;
constexpr int NTOT = BB * HW;
constexpr float EPS = 1e-8f;

#define T 64          // output tile edge
#define HALO_L 6      // left/top halo
#define REG 80        // region edge = 64 + 6 + 10
#define NPX (REG * REG)   // 6400
#define TPB 1024
#define SLOTS 7       // ceil(6400/1024)
#define NBLK 256      // 4 images x 8x8 tiles
#define XR 82         // x1 staging edge (region + 1-ring for 3x3 gradient)
#define XN (XR * XR)  // 6724 <= 12800 floats available in spa

// phase: 0 = first (u,p zero-init, write back), 1 = middle (load, write
// back), 2 = last (load, 5 u-phases + 4 p-phases, fused avgpool -> out).
__global__ __launch_bounds__(TPB, 1) void k_fused(
    const float* __restrict__ x,
    float2* __restrict__ ug, float4* __restrict__ pg,
    const float* __restrict__ lam_p, const float* __restrict__ tau_p,
    const float* __restrict__ theta_p,
    const float* __restrict__ wxp, const float* __restrict__ wyp,
    float* __restrict__ out, int phase)
{
    __shared__ float2 su[NPX];    // (u1,u2)
    __shared__ float2 spa[NPX];   // (p11,p21); doubles as x1 staging buffer
    __shared__ float2 spb[NPX];   // (p12,p22)   -> 153.6 KB total

    const int tid  = threadIdx.x;
    const int blk  = blockIdx.x;
    const int bimg = blk >> 6;
    const int t    = blk & 63;
    const int gi0  = (t >> 3) * T;
    const int gj0  = (t & 7) * T;

    const float lam = lam_p[0], theta = theta_p[0];
    const float r   = tau_p[0] / theta;
    const float tl  = theta * lam;
    const float wx0 = wxp[0], wx1 = wxp[1], wx2 = wxp[2];
    const float wy0 = wyp[0], wy1 = wyp[1], wy2 = wyp[2];

    const int gbase = bimg * HW;
    const float* x0p = x + (size_t)bimg * 2 * HW;
    const float* x1p = x0p + HW;

    int  lis[SLOTS], ljs[SLOTS], gofs[SLOTS];
    bool inb[SLOTS];
    float2 ruv[SLOTS], rpa[SLOTS], rpb[SLOTS];  // own-pixel mirrors
    float  x0v[SLOTS];

    // ---- pass 1: stage x1 into spa-as-float; precompute per-slot indices;
    //      issue state loads early (consumed in pass 3, overlap statics) ----
    #pragma unroll
    for (int s = 0; s < SLOTS; ++s) {
        int idx = tid + s * TPB;
        if (idx < XN) {
            int li = idx / XR, lj = idx - li * XR;
            int gi = gi0 + li - (HALO_L + 1), gj = gj0 + lj - (HALO_L + 1);
            bool in = ((unsigned)gi < HH) & ((unsigned)gj < WW);
            ((float*)spa)[idx] = in ? x1p[gi * WW + gj] : 0.f;
        }
        if (idx < NPX) {
            int li = idx / REG, lj = idx - li * REG;
            lis[s] = li; ljs[s] = lj;
            int gi = gi0 + li - HALO_L, gj = gj0 + lj - HALO_L;
            bool in = ((unsigned)gi < HH) & ((unsigned)gj < WW);
            inb[s] = in;
            int gl = gi * WW + gj;            // valid only when in
            gofs[s] = gl;
            float2 uv = make_float2(0.f, 0.f);
            float4 p4 = make_float4(0.f, 0.f, 0.f, 0.f);
            float xv = 0.f;
            if (in) {
                xv = x0p[gl];
                if (phase != 0) {
                    uv = ug[gbase + gl];
                    p4 = pg[gbase + gl];
                }
            }
            x0v[s] = xv;
            ruv[s] = uv;
            rpa[s] = make_float2(p4.x, p4.y);
            rpb[s] = make_float2(p4.z, p4.w);
        }
    }
    __syncthreads();

    // ---- pass 2: statics (gx,gy,rc,th,1/nm) from staged x1 ---------------
    float rgx[SLOTS], rgy[SLOTS], rrc[SLOTS], rth[SLOTS], rnv[SLOTS];
    const float* stg = (const float*)spa;
    #pragma unroll
    for (int s = 0; s < SLOTS; ++s) {
        int idx = tid + s * TPB;
        if (idx < NPX) {
            int sc = (lis[s] + 1) * XR + (ljs[s] + 1);
            float a00 = stg[sc - XR - 1], a01 = stg[sc - XR], a02 = stg[sc - XR + 1];
            float a10 = stg[sc - 1],      a11 = stg[sc],      a12 = stg[sc + 1];
            float a20 = stg[sc + XR - 1], a21 = stg[sc + XR], a22 = stg[sc + XR + 1];
            const float c6 = 1.f / 6.f;
            float gxv = c6 * (-a00 + a02 - 2.f * a10 + 2.f * a12 - a20 + a22);
            float gyv = c6 * (-a00 - 2.f * a01 - a02 + a20 + 2.f * a21 + a22);
            float nm  = gxv * gxv + gyv * gyv + EPS;
            rgx[s] = gxv; rgy[s] = gyv;
            rrc[s] = a11 - x0v[s];           // zero-padded conv semantics held
            rth[s] = tl * nm;
            rnv[s] = __builtin_amdgcn_rcpf(nm);
        }
    }
    __syncthreads();

    // ---- pass 3: fill LDS state (overwrites staging) ---------------------
    #pragma unroll
    for (int s = 0; s < SLOTS; ++s) {
        int idx = tid + s * TPB;
        if (idx < NPX) {
            su[idx]  = ruv[s];
            spa[idx] = rpa[s];
            spb[idx] = rpb[s];
        }
    }
    __syncthreads();

    // ---- 5 fused iterations ---------------------------------------------
    for (int k = 1; k <= 5; ++k) {
        // u-phase over li,lj in [k, REG-2k]  (valid cone of u^k)
        const int lo = k, hi_u = REG - 2 * k;
        #pragma unroll
        for (int s = 0; s < SLOTS; ++s) {
            int idx = tid + s * TPB;
            if (idx >= NPX) continue;
            int li = lis[s], lj = ljs[s];
            if (li < lo || li > hi_u || lj < lo || lj > hi_u) continue;
            float2 uv = ruv[s];
            float rho = rrc[s] + rgx[s] * uv.x + rgy[s] * uv.y;
            // th>0 always (nm>=EPS, tl>0), so rho==0 takes the inside branch:
            // copysignf(tl,0) is never selected -> sign(0)=0 handled.
            float d = (fabsf(rho) < rth[s]) ? rho * rnv[s] : copysignf(tl, rho);
            float v1 = uv.x - d * rgx[s];
            float v2 = uv.y - d * rgy[s];
            float2 pal = spa[idx - 1],   par = spa[idx + 1];
            float2 pbt = spb[idx - REG], pbb = spb[idx + REG];
            float2 pac = rpa[s],         pbc = rpb[s];
            float div1 = wx0 * pal.x + wx1 * pac.x + wx2 * par.x
                       + wy0 * pbt.x + wy1 * pbc.x + wy2 * pbb.x;
            float div2 = wx0 * pal.y + wx1 * pac.y + wx2 * par.y
                       + wy0 * pbt.y + wy1 * pbc.y + wy2 * pbb.y;
            float nu1 = v1 + theta * div1;
            float nu2 = v2 + theta * div2;
            if (!inb[s]) { nu1 = 0.f; nu2 = 0.f; }   // zero-padding semantics
            float2 nuv = make_float2(nu1, nu2);
            ruv[s] = nuv; su[idx] = nuv;
        }
        __syncthreads();
        if (phase == 2 && k == 5) break;   // 20th p-update is dead code

        // p-phase over li,lj in [k, REG-1-2k]  (valid cone of p^k)
        const int hi_p = REG - 1 - 2 * k;
        #pragma unroll
        for (int s = 0; s < SLOTS; ++s) {
            int idx = tid + s * TPB;
            if (idx >= NPX) continue;
            int li = lis[s], lj = ljs[s];
            if (li < lo || li > hi_p || lj < lo || lj > hi_p) continue;
            float2 uc = ruv[s];
            float2 uR = su[idx + 1];
            float2 uB = su[idx + REG];
            float gu1x = uR.x - uc.x, gu1y = uB.x - uc.x;
            float gu2x = uR.y - uc.y, gu2y = uB.y - uc.y;
            float d1 = 1.f + r * (fabsf(gu1x) + fabsf(gu1y));
            float id1 = __builtin_amdgcn_rcpf(d1);
            float np11 = (rpa[s].x + r * gu1x) * id1;
            float np12 = (rpb[s].x + r * gu1y) * id1;
            float d2 = 1.f + r * (fabsf(gu2x) + fabsf(gu2y));
            float id2 = __builtin_amdgcn_rcpf(d2);
            float np21 = (rpa[s].y + r * gu2x) * id2;
            float np22 = (rpb[s].y + r * gu2y) * id2;
            if (!inb[s]) { np11 = 0.f; np12 = 0.f; np21 = 0.f; np22 = 0.f; }
            float2 npa = make_float2(np11, np21);
            float2 npb = make_float2(np12, np22);
            rpa[s] = npa; rpb[s] = npb;
            spa[idx] = npa; spb[idx] = npb;
        }
        __syncthreads();
    }

    // ---- epilogue --------------------------------------------------------
    if (phase != 2) {
        // write back interior [0,63]^2 (li,lj in [6,69]) from mirrors
        #pragma unroll
        for (int s = 0; s < SLOTS; ++s) {
            int idx = tid + s * TPB;
            if (idx >= NPX) continue;
            int li = lis[s], lj = ljs[s];
            if (li < HALO_L || li >= HALO_L + T || lj < HALO_L || lj >= HALO_L + T) continue;
            int gl = gofs[s];
            ug[gbase + gl] = ruv[s];
            pg[gbase + gl] = make_float4(rpa[s].x, rpa[s].y, rpb[s].x, rpb[s].y);
        }
    } else {
        // fused avgpool(3,1,1, /9 always); u^5 valid on [-1,64] — exact fit
        const float inv9 = 1.f / 9.f;
        #pragma unroll
        for (int s = 0; s < SLOTS; ++s) {
            int idx = tid + s * TPB;
            if (idx >= NPX) continue;
            int li = lis[s], lj = ljs[s];
            if (li < HALO_L || li >= HALO_L + T || lj < HALO_L || lj >= HALO_L + T) continue;
            float2 a0 = su[idx - REG - 1], a1 = su[idx - REG], a2 = su[idx - REG + 1];
            float2 b0 = su[idx - 1],       b1 = su[idx],       b2 = su[idx + 1];
            float2 c0 = su[idx + REG - 1], c1 = su[idx + REG], c2 = su[idx + REG + 1];
            float s1 = a0.x + a1.x + a2.x + b0.x + b1.x + b2.x + c0.x + c1.x + c2.x;
            float s2 = a0.y + a1.y + a2.y + b0.y + b1.y + b2.y + c0.y + c1.y + c2.y;
            int gl = gofs[s];
            out[(size_t)bimg * 2 * HW + gl]      = s1 * inv9;
            out[(size_t)bimg * 2 * HW + HW + gl] = s2 * inv9;
        }
    }
}

// --------------------------------------------------------------- launch ---
extern "C" void kernel_launch(void* const* d_in, const int* in_sizes, int n_in,
                              void* d_out, int out_size, void* d_ws, size_t ws_size,
                              hipStream_t stream) {
    const float* x     = (const float*)d_in[0];
    const float* lam   = (const float*)d_in[1];
    const float* tau   = (const float*)d_in[2];
    const float* theta = (const float*)d_in[3];
    const float* wx    = (const float*)d_in[4];
    const float* wy    = (const float*)d_in[5];
    float* out = (float*)d_out;

    float*  ws = (float*)d_ws;
    float2* ug = (float2*)ws;                         // 8 MB
    float4* pg = (float4*)(ws + (size_t)2 * NTOT);    // 16 MB

    for (int c = 0; c < 4; ++c) {
        int phase = (c == 0) ? 0 : (c == 3) ? 2 : 1;
        k_fused<<<dim3(NBLK), dim3(TPB), 0, stream>>>(
            x, ug, pg, lam, tau, theta, wx, wy, out, phase);
    }
}